// Round 1
// 1315.855 us; speedup vs baseline: 1.0560x; 1.0560x over previous
//
#include <hip/hip_runtime.h>
#include <hip/hip_bf16.h>
#include <stdint.h>

// Problem constants (reference: B=8, L=12288)
#define BB 8
#define LL 12288
#define NCB 6             // column blocks: 256 thr * 8 cols = 2048 cols each
#define NCH 128           // i-chunks
#define RPC (LL / NCH)    // 96 rows per chunk

// Workspace layout in floats.  Only FLAGS+NORM2 need zeroing (128 B).
#define WS_FLAGS 0
#define WS_NORM2 16
#define WS_SACC  32                         // BB*LL reduced numerators
#define WS_CNT   (WS_SACC + BB * LL)        // LL reduced counts
#define WS_PART  (WS_CNT + LL)              // NCH*BB*LL chunk partials
#define WS_CNTP  (WS_PART + NCH * BB * LL)  // NCH*LL chunk counts

__device__ __forceinline__ float bf2f(uint16_t u) {
  union { uint32_t i; float f; } v; v.i = ((uint32_t)u) << 16; return v.f;
}

// Unpack 8 bf16 (packed in uint4) to floats.  High half of each u32 is free
// (f32 bits = u & 0xFFFF0000); low half is u << 16.
__device__ __forceinline__ void unpack8(uint4 u, float* f) {
  union { uint32_t i; float v; } t;
  t.i = u.x << 16;          f[0] = t.v;
  t.i = u.x & 0xFFFF0000u;  f[1] = t.v;
  t.i = u.y << 16;          f[2] = t.v;
  t.i = u.y & 0xFFFF0000u;  f[3] = t.v;
  t.i = u.z << 16;          f[4] = t.v;
  t.i = u.z & 0xFFFF0000u;  f[5] = t.v;
  t.i = u.w << 16;          f[6] = t.v;
  t.i = u.w & 0xFFFF0000u;  f[7] = t.v;
}

// ---------------------------------------------------------------------------
// Dtype detection by byte patterns (round-0 notes).  flags[0]=mask byte
// width, flags[1]=floats-are-bf16.  (R2 FETCH_SIZE confirmed bf16+bf16 on
// this dataset; kept for robustness, costs ~5 us.)
// ---------------------------------------------------------------------------
__global__ void detect_kernel(const uint8_t* __restrict__ mask,
                              const uint8_t* __restrict__ adj,
                              int* __restrict__ flags) {
  __shared__ int s[6];
  int tid = threadIdx.x;
  if (tid < 6) s[tid] = 0;
  __syncthreads();
  int c[4] = {0, 0, 0, 0};
  int big = 0, hi = 0;
  const int N = 65536;
  for (int idx = tid; idx < N; idx += blockDim.x) {
    uint8_t v = mask[idx];
    if (v) { c[idx & 3]++; if (v >= 2) big++; }
    uint8_t a = adj[idx];
    if ((idx & 3) == 1 && a >= 0x80) hi++;
  }
  atomicAdd(&s[0], c[0]); atomicAdd(&s[1], c[1]);
  atomicAdd(&s[2], c[2]); atomicAdd(&s[3], c[3]);
  atomicAdd(&s[4], big);  atomicAdd(&s[5], hi);
  __syncthreads();
  if (tid == 0) {
    int width;
    int nzoff = s[1] + s[2] + s[3];
    if (nzoff == 0)             width = 4;  // int32
    else if (s[0] + s[1] == 0)  width = 4;  // f32 mask
    else if (s[4] == 0)         width = 1;  // u8 bool
    else                        width = 2;  // bf16 mask
    flags[0] = width;
    flags[1] = (s[5] == 0) ? 1 : 0;
  }
}

// ---------------------------------------------------------------------------
// Stage 1: per-column masked partial sums, atomic-free.  8 cols/thread via
// 16-B loads; pred chunk in LDS [i][b]; partials stored coalesced per
// (chunk, colblock) slice.
//
// R(new): SPARSITY SKIP — adj_mask density is ~1%, so a lane's 8-column
// group is all-zero with P=0.99^8~92%.  The mask bits are already in
// registers (mandatory traffic); predicating the adj load on them means
// exec-masked lanes issue no memory requests, and HBM lines touched by no
// lane are never fetched.  At 64-128 B line granularity this skips
// ~70-90% of adj bytes.  Math is bit-identical: skipped lanes keep a[k]=0,
// exactly what the unconditional path computed via (m[k] ? a[k] : 0).
// ---------------------------------------------------------------------------
template <int MW, int FB>
__device__ void s1loop(const uint8_t* __restrict__ mask,
                       const uint8_t* __restrict__ adj,
                       float* __restrict__ part, float* __restrict__ cntp,
                       const float* __restrict__ sp,  // LDS [RPC][BB]
                       int j0, int i0, int ch) {
  float acc[BB][8];
  float c8[8] = {0.f, 0.f, 0.f, 0.f, 0.f, 0.f, 0.f, 0.f};
#pragma unroll
  for (int b = 0; b < BB; b++)
#pragma unroll
    for (int k = 0; k < 8; k++) acc[b][k] = 0.f;

#pragma unroll 2
  for (int il = 0; il < RPC; ++il) {
    size_t e = (size_t)(i0 + il) * LL + j0;
    // mask first (mandatory traffic; feeds the adj-load predicate)
    int m[8];
    if (MW == 1) {
      uint2 u = *reinterpret_cast<const uint2*>(mask + e);
      m[0] = (u.x & 0x000000FFu) != 0; m[1] = (u.x & 0x0000FF00u) != 0;
      m[2] = (u.x & 0x00FF0000u) != 0; m[3] = (u.x & 0xFF000000u) != 0;
      m[4] = (u.y & 0x000000FFu) != 0; m[5] = (u.y & 0x0000FF00u) != 0;
      m[6] = (u.y & 0x00FF0000u) != 0; m[7] = (u.y & 0xFF000000u) != 0;
    } else if (MW == 2) {
      uint4 u = *reinterpret_cast<const uint4*>(mask + e * 2);
      m[0] = (u.x & 0xFFFFu) != 0; m[1] = (u.x >> 16) != 0;
      m[2] = (u.y & 0xFFFFu) != 0; m[3] = (u.y >> 16) != 0;
      m[4] = (u.z & 0xFFFFu) != 0; m[5] = (u.z >> 16) != 0;
      m[6] = (u.w & 0xFFFFu) != 0; m[7] = (u.w >> 16) != 0;
    } else {
      uint4 u0 = *reinterpret_cast<const uint4*>(mask + e * 4);
      uint4 u1 = *reinterpret_cast<const uint4*>(mask + e * 4 + 16);
      m[0] = u0.x != 0; m[1] = u0.y != 0; m[2] = u0.z != 0; m[3] = u0.w != 0;
      m[4] = u1.x != 0; m[5] = u1.y != 0; m[6] = u1.z != 0; m[7] = u1.w != 0;
    }
    int any_lo = m[0] | m[1] | m[2] | m[3];
    int any_hi = m[4] | m[5] | m[6] | m[7];

    float a[8] = {0.f, 0.f, 0.f, 0.f, 0.f, 0.f, 0.f, 0.f};
    if (FB) {
      // bf16 adj: one 16-B load covers all 8 cols; skip if group all-zero.
      if (any_lo | any_hi) {
        uint4 u = *reinterpret_cast<const uint4*>(adj + e * 2);
        unpack8(u, a);
      }
    } else {
      // f32 adj: predicate each 16-B half independently (P(skip)=0.99^4~96%).
      if (any_lo) {
        float4 f0 = *reinterpret_cast<const float4*>(adj + e * 4);
        a[0] = f0.x; a[1] = f0.y; a[2] = f0.z; a[3] = f0.w;
      }
      if (any_hi) {
        float4 f1 = *reinterpret_cast<const float4*>(adj + e * 4 + 16);
        a[4] = f1.x; a[5] = f1.y; a[6] = f1.z; a[7] = f1.w;
      }
    }
#pragma unroll
    for (int k = 0; k < 8; k++) {
      a[k] = m[k] ? a[k] : 0.f;
      c8[k] += m[k] ? 1.f : 0.f;
    }
    // broadcast LDS reads: pred[i][0..7]
    float4 p0 = *reinterpret_cast<const float4*>(sp + il * BB);
    float4 p1 = *reinterpret_cast<const float4*>(sp + il * BB + 4);
    float pv[BB] = {p0.x, p0.y, p0.z, p0.w, p1.x, p1.y, p1.z, p1.w};
#pragma unroll
    for (int b = 0; b < BB; b++)
#pragma unroll
      for (int k = 0; k < 8; k++) acc[b][k] = fmaf(pv[b], a[k], acc[b][k]);
  }
  // Coalesced partial stores: thread owns 8 contiguous cols -> 2x float4.
#pragma unroll
  for (int b = 0; b < BB; b++) {
    float* dst = part + ((size_t)ch * BB + b) * LL + j0;
    *reinterpret_cast<float4*>(dst)     = make_float4(acc[b][0], acc[b][1], acc[b][2], acc[b][3]);
    *reinterpret_cast<float4*>(dst + 4) = make_float4(acc[b][4], acc[b][5], acc[b][6], acc[b][7]);
  }
  float* cdst = cntp + (size_t)ch * LL + j0;
  *reinterpret_cast<float4*>(cdst)     = make_float4(c8[0], c8[1], c8[2], c8[3]);
  *reinterpret_cast<float4*>(cdst + 4) = make_float4(c8[4], c8[5], c8[6], c8[7]);
}

__global__ __launch_bounds__(256) void stage1(const uint8_t* __restrict__ mask,
                                              const uint8_t* __restrict__ adj,
                                              const uint8_t* __restrict__ pred,
                                              float* __restrict__ ws) {
  __shared__ float sp[RPC * BB];  // 3 KB
  const int* fl = (const int*)ws;
  int mw = fl[0], fb = fl[1];
  int cb = blockIdx.x % NCB;
  int ch = blockIdx.x / NCB;
  int j0 = cb * 2048 + threadIdx.x * 8;
  int i0 = ch * RPC;
  for (int idx = threadIdx.x; idx < RPC * BB; idx += 256) {
    int b = idx / RPC, il = idx % RPC;
    float p = fb ? bf2f(reinterpret_cast<const uint16_t*>(pred)[b * LL + i0 + il])
                 : reinterpret_cast<const float*>(pred)[b * LL + i0 + il];
    sp[il * BB + b] = p;
  }
  __syncthreads();
  float* part = ws + WS_PART;
  float* cntp = ws + WS_CNTP;
  if (fb) {
    if (mw == 1)      s1loop<1, 1>(mask, adj, part, cntp, sp, j0, i0, ch);
    else if (mw == 2) s1loop<2, 1>(mask, adj, part, cntp, sp, j0, i0, ch);
    else              s1loop<4, 1>(mask, adj, part, cntp, sp, j0, i0, ch);
  } else {
    if (mw == 1)      s1loop<1, 0>(mask, adj, part, cntp, sp, j0, i0, ch);
    else if (mw == 2) s1loop<2, 0>(mask, adj, part, cntp, sp, j0, i0, ch);
    else              s1loop<4, 0>(mask, adj, part, cntp, sp, j0, i0, ch);
  }
}

// ---------------------------------------------------------------------------
// Reduce chunk partials: sacc[b*LL+j] = sum_c part[c][b][j]; cnt[j] likewise.
// ---------------------------------------------------------------------------
__global__ __launch_bounds__(256) void reduce_kernel(float* __restrict__ ws) {
  int idx = blockIdx.x * 256 + threadIdx.x;  // [0, BB*LL)
  const float* part = ws + WS_PART;
  float s = 0.f;
#pragma unroll 8
  for (int c = 0; c < NCH; c++) s += part[(size_t)c * (BB * LL) + idx];
  ws[WS_SACC + idx] = s;
  if (idx < LL) {
    const float* cntp = ws + WS_CNTP;
    float cs = 0.f;
#pragma unroll 8
    for (int c = 0; c < NCH; c++) cs += cntp[(size_t)c * LL + idx];
    ws[WS_CNT + idx] = cs;
  }
}

// ---------------------------------------------------------------------------
// Stage 2+3 fused: per-column candidates + diff accumulation.
// ---------------------------------------------------------------------------
__global__ __launch_bounds__(256) void stage23(const uint8_t* __restrict__ mask,
                                               const uint8_t* __restrict__ pred,
                                               const uint8_t* __restrict__ sim,
                                               float* __restrict__ ws) {
  const int* fl = (const int*)ws;
  int mw = fl[0], fb = fl[1];
  float* sacc = ws + WS_SACC;
  float* cntw = ws + WS_CNT;
  float* norm2 = ws + WS_NORM2;
  __shared__ float ssim[64];
  if (threadIdx.x < 64) {
    ssim[threadIdx.x] = fb ? bf2f(((const uint16_t*)sim)[threadIdx.x])
                           : ((const float*)sim)[threadIdx.x];
  }
  __syncthreads();
  int j = blockIdx.x * 256 + threadIdx.x;
  size_t ed = (size_t)j * LL + j;
  int mjj;
  if (mw == 1)      mjj = mask[ed] != 0;
  else if (mw == 2) mjj = ((const uint16_t*)mask)[ed] != 0;
  else              mjj = ((const uint32_t*)mask)[ed] != 0;
  float add = mjj ? 0.f : 1.f;
  float c = cntw[j] + add;
  float pj[BB], cv[BB];
#pragma unroll
  for (int b = 0; b < BB; b++)
    pj[b] = fb ? bf2f(((const uint16_t*)pred)[b * LL + j])
               : ((const float*)pred)[b * LL + j];
#pragma unroll
  for (int k = 0; k < BB; k++) cv[k] = (sacc[k * LL + j] + pj[k] * add) / c;
#pragma unroll
  for (int b = 0; b < BB; b++) {
    float t = pj[b];
#pragma unroll
    for (int k = 0; k < BB; k++) t = fmaf(-ssim[b * 8 + k], cv[k], t);
    float v = t * t;
#pragma unroll
    for (int off = 32; off > 0; off >>= 1) v += __shfl_down(v, off, 64);
    if ((threadIdx.x & 63) == 0) unsafeAtomicAdd(&norm2[b], v);
  }
}

// ---------------------------------------------------------------------------
// Stage 4: finalize scalar output.
// ---------------------------------------------------------------------------
__global__ void stage4(const uint8_t* __restrict__ sim,
                       uint8_t* __restrict__ out, float* __restrict__ ws) {
  if (threadIdx.x != 0) return;
  const int* fl = (const int*)ws;
  int fb = fl[1];
  float* norm2 = ws + WS_NORM2;
  float total = 0.f, cntv = 0.f;
  for (int b = 0; b < BB; b++) {
    float rs = 0.f;
    for (int k = 0; k < 8; k++)
      rs += fb ? bf2f(((const uint16_t*)sim)[b * 8 + k])
               : ((const float*)sim)[b * 8 + k];
    if (rs != 0.f) { cntv += 1.f; total += sqrtf(norm2[b]); }
  }
  float res = (cntv == 0.f) ? 0.f : total / fmaxf(cntv, 1.f);
  if (fb) *reinterpret_cast<__hip_bfloat16*>(out) = __float2bfloat16(res);
  else    *reinterpret_cast<float*>(out) = res;
}

extern "C" void kernel_launch(void* const* d_in, const int* in_sizes, int n_in,
                              void* d_out, int out_size, void* d_ws,
                              size_t ws_size, hipStream_t stream) {
  const uint8_t* pred = (const uint8_t*)d_in[0];
  const uint8_t* sim  = (const uint8_t*)d_in[1];
  const uint8_t* adj  = (const uint8_t*)d_in[2];
  const uint8_t* mask = (const uint8_t*)d_in[3];
  float* ws = (float*)d_ws;

  hipMemsetAsync(d_ws, 0, 32 * sizeof(float), stream);  // flags + norm2 only
  detect_kernel<<<1, 256, 0, stream>>>(mask, adj, (int*)d_ws);
  stage1<<<NCB * NCH, 256, 0, stream>>>(mask, adj, pred, ws);
  reduce_kernel<<<BB * LL / 256, 256, 0, stream>>>(ws);
  stage23<<<LL / 256, 256, 0, stream>>>(mask, pred, sim, ws);
  stage4<<<1, 64, 0, stream>>>(sim, (uint8_t*)d_out, ws);
}

// Round 4
// 1315.361 us; speedup vs baseline: 1.0563x; 1.0004x over previous
//
#include <hip/hip_runtime.h>
#include <hip/hip_bf16.h>
#include <stdint.h>

// Problem constants (reference: B=8, L=12288)
#define BB 8
#define LL 12288
#define NCB 12            // column blocks: 256 thr * 4 cols = 1024 cols each
#define NCH 64            // i-chunks
#define RPC (LL / NCH)    // 192 rows per chunk

// Workspace layout in floats.  Only FLAGS+NORM2 need zeroing (128 B).
#define WS_FLAGS 0
#define WS_NORM2 16
#define WS_SACC  32                         // BB*LL reduced numerators
#define WS_CNT   (WS_SACC + BB * LL)        // LL reduced counts
#define WS_PART  (WS_CNT + LL)              // NCH*BB*LL chunk partials
#define WS_CNTP  (WS_PART + NCH * BB * LL)  // NCH*LL chunk counts

__device__ __forceinline__ float bf2f(uint16_t u) {
  union { uint32_t i; float f; } v; v.i = ((uint32_t)u) << 16; return v.f;
}

// ---------------------------------------------------------------------------
// Dtype detection by byte patterns (round-0 notes).  flags[0]=mask byte
// width, flags[1]=floats-are-bf16.
// ---------------------------------------------------------------------------
__global__ void detect_kernel(const uint8_t* __restrict__ mask,
                              const uint8_t* __restrict__ adj,
                              int* __restrict__ flags) {
  __shared__ int s[6];
  int tid = threadIdx.x;
  if (tid < 6) s[tid] = 0;
  __syncthreads();
  int c[4] = {0, 0, 0, 0};
  int big = 0, hi = 0;
  const int N = 65536;
  for (int idx = tid; idx < N; idx += blockDim.x) {
    uint8_t v = mask[idx];
    if (v) { c[idx & 3]++; if (v >= 2) big++; }
    uint8_t a = adj[idx];
    if ((idx & 3) == 1 && a >= 0x80) hi++;
  }
  atomicAdd(&s[0], c[0]); atomicAdd(&s[1], c[1]);
  atomicAdd(&s[2], c[2]); atomicAdd(&s[3], c[3]);
  atomicAdd(&s[4], big);  atomicAdd(&s[5], hi);
  __syncthreads();
  if (tid == 0) {
    int width;
    int nzoff = s[1] + s[2] + s[3];
    if (nzoff == 0)             width = 4;  // int32
    else if (s[0] + s[1] == 0)  width = 4;  // f32 mask
    else if (s[4] == 0)         width = 1;  // u8 bool
    else                        width = 2;  // bf16 mask
    flags[0] = width;
    flags[1] = (s[5] == 0) ? 1 : 0;
  }
}

// ---------------------------------------------------------------------------
// Stage 1: per-column masked partial sums, atomic-free.  4 cols/thread;
// pred chunk in LDS [i][b]; partials stored coalesced per (chunk, colblock)
// slice.
//
// R1: SPARSITY SKIP — adj_mask density ~1%; a lane's 4-col group is all-zero
// with P=0.99^4~96%.  Mask bits (mandatory traffic) predicate the adj load:
// exec-masked lanes issue no requests, and lines no lane touches are never
// fetched.  Bit-identical: skipped lanes keep a[k]=0 = old (m?a:0).
// R2/R3: NCH 128->64 / NCB 6->12 (grid stays 768, balanced 3 blocks/CU)
// halves the split-K partials round-trip (57.6->28.8 MB each way).
// (R3: dropped nontemporal-load hints — speculative benefit, and the only
// codegen novelty vs the R1-verified binary after two container failures.)
// ---------------------------------------------------------------------------
template <int MW, int FB>
__device__ void s1loop(const uint8_t* __restrict__ mask,
                       const uint8_t* __restrict__ adj,
                       float* __restrict__ part, float* __restrict__ cntp,
                       const float* __restrict__ sp,  // LDS [RPC][BB]
                       int j0, int i0, int ch) {
  float acc[BB][4];
  float c4[4] = {0.f, 0.f, 0.f, 0.f};
#pragma unroll
  for (int b = 0; b < BB; b++)
#pragma unroll
    for (int k = 0; k < 4; k++) acc[b][k] = 0.f;

#pragma unroll 2
  for (int il = 0; il < RPC; ++il) {
    size_t e = (size_t)(i0 + il) * LL + j0;
    // mask first (mandatory traffic; feeds the adj-load predicate)
    int m[4];
    if (MW == 1) {
      uint32_t u = *reinterpret_cast<const uint32_t*>(mask + e);
      m[0] = (u & 0x000000FFu) != 0; m[1] = (u & 0x0000FF00u) != 0;
      m[2] = (u & 0x00FF0000u) != 0; m[3] = (u & 0xFF000000u) != 0;
    } else if (MW == 2) {
      uint2 u = *reinterpret_cast<const uint2*>(mask + e * 2);
      m[0] = (u.x & 0xFFFFu) != 0; m[1] = (u.x >> 16) != 0;
      m[2] = (u.y & 0xFFFFu) != 0; m[3] = (u.y >> 16) != 0;
    } else {
      uint4 u = *reinterpret_cast<const uint4*>(mask + e * 4);
      m[0] = u.x != 0; m[1] = u.y != 0; m[2] = u.z != 0; m[3] = u.w != 0;
    }
    int any = m[0] | m[1] | m[2] | m[3];

    float a[4] = {0.f, 0.f, 0.f, 0.f};
    if (FB) {
      // bf16 adj: one 8-B load covers the 4 cols; skip if group all-zero.
      if (any) {
        uint2 u = *reinterpret_cast<const uint2*>(adj + e * 2);
        union { uint32_t i; float v; } t;
        t.i = u.x << 16;          a[0] = t.v;
        t.i = u.x & 0xFFFF0000u;  a[1] = t.v;
        t.i = u.y << 16;          a[2] = t.v;
        t.i = u.y & 0xFFFF0000u;  a[3] = t.v;
      }
    } else {
      // f32 adj: one 16-B load; skip if group all-zero (P=0.99^4~96%).
      if (any) {
        float4 f = *reinterpret_cast<const float4*>(adj + e * 4);
        a[0] = f.x; a[1] = f.y; a[2] = f.z; a[3] = f.w;
      }
    }
#pragma unroll
    for (int k = 0; k < 4; k++) {
      a[k] = m[k] ? a[k] : 0.f;
      c4[k] += m[k] ? 1.f : 0.f;
    }
    // broadcast LDS reads: pred[i][0..7]
    float4 p0 = *reinterpret_cast<const float4*>(sp + il * BB);
    float4 p1 = *reinterpret_cast<const float4*>(sp + il * BB + 4);
    float pv[BB] = {p0.x, p0.y, p0.z, p0.w, p1.x, p1.y, p1.z, p1.w};
#pragma unroll
    for (int b = 0; b < BB; b++)
#pragma unroll
      for (int k = 0; k < 4; k++) acc[b][k] = fmaf(pv[b], a[k], acc[b][k]);
  }
  // Coalesced partial stores: thread owns 4 contiguous cols -> 1x float4.
#pragma unroll
  for (int b = 0; b < BB; b++) {
    float* dst = part + ((size_t)ch * BB + b) * LL + j0;
    *reinterpret_cast<float4*>(dst) =
        make_float4(acc[b][0], acc[b][1], acc[b][2], acc[b][3]);
  }
  float* cdst = cntp + (size_t)ch * LL + j0;
  *reinterpret_cast<float4*>(cdst) = make_float4(c4[0], c4[1], c4[2], c4[3]);
}

__global__ __launch_bounds__(256) void stage1(const uint8_t* __restrict__ mask,
                                              const uint8_t* __restrict__ adj,
                                              const uint8_t* __restrict__ pred,
                                              float* __restrict__ ws) {
  __shared__ float sp[RPC * BB];  // 6 KB
  const int* fl = (const int*)ws;
  int mw = fl[0], fb = fl[1];
  int cb = blockIdx.x % NCB;
  int ch = blockIdx.x / NCB;
  int j0 = cb * 1024 + threadIdx.x * 4;
  int i0 = ch * RPC;
  for (int idx = threadIdx.x; idx < RPC * BB; idx += 256) {
    int b = idx / RPC, il = idx % RPC;
    float p = fb ? bf2f(reinterpret_cast<const uint16_t*>(pred)[b * LL + i0 + il])
                 : reinterpret_cast<const float*>(pred)[b * LL + i0 + il];
    sp[il * BB + b] = p;
  }
  __syncthreads();
  float* part = ws + WS_PART;
  float* cntp = ws + WS_CNTP;
  if (fb) {
    if (mw == 1)      s1loop<1, 1>(mask, adj, part, cntp, sp, j0, i0, ch);
    else if (mw == 2) s1loop<2, 1>(mask, adj, part, cntp, sp, j0, i0, ch);
    else              s1loop<4, 1>(mask, adj, part, cntp, sp, j0, i0, ch);
  } else {
    if (mw == 1)      s1loop<1, 0>(mask, adj, part, cntp, sp, j0, i0, ch);
    else if (mw == 2) s1loop<2, 0>(mask, adj, part, cntp, sp, j0, i0, ch);
    else              s1loop<4, 0>(mask, adj, part, cntp, sp, j0, i0, ch);
  }
}

// ---------------------------------------------------------------------------
// Reduce chunk partials: sacc[b*LL+j] = sum_c part[c][b][j]; cnt[j] likewise.
// ---------------------------------------------------------------------------
__global__ __launch_bounds__(256) void reduce_kernel(float* __restrict__ ws) {
  int idx = blockIdx.x * 256 + threadIdx.x;  // [0, BB*LL)
  const float* part = ws + WS_PART;
  float s = 0.f;
#pragma unroll 8
  for (int c = 0; c < NCH; c++) s += part[(size_t)c * (BB * LL) + idx];
  ws[WS_SACC + idx] = s;
  if (idx < LL) {
    const float* cntp = ws + WS_CNTP;
    float cs = 0.f;
#pragma unroll 8
    for (int c = 0; c < NCH; c++) cs += cntp[(size_t)c * LL + idx];
    ws[WS_CNT + idx] = cs;
  }
}

// ---------------------------------------------------------------------------
// Stage 2+3 fused: per-column candidates + diff accumulation.
// ---------------------------------------------------------------------------
__global__ __launch_bounds__(256) void stage23(const uint8_t* __restrict__ mask,
                                               const uint8_t* __restrict__ pred,
                                               const uint8_t* __restrict__ sim,
                                               float* __restrict__ ws) {
  const int* fl = (const int*)ws;
  int mw = fl[0], fb = fl[1];
  float* sacc = ws + WS_SACC;
  float* cntw = ws + WS_CNT;
  float* norm2 = ws + WS_NORM2;
  __shared__ float ssim[64];
  if (threadIdx.x < 64) {
    ssim[threadIdx.x] = fb ? bf2f(((const uint16_t*)sim)[threadIdx.x])
                           : ((const float*)sim)[threadIdx.x];
  }
  __syncthreads();
  int j = blockIdx.x * 256 + threadIdx.x;
  size_t ed = (size_t)j * LL + j;
  int mjj;
  if (mw == 1)      mjj = mask[ed] != 0;
  else if (mw == 2) mjj = ((const uint16_t*)mask)[ed] != 0;
  else              mjj = ((const uint32_t*)mask)[ed] != 0;
  float add = mjj ? 0.f : 1.f;
  float c = cntw[j] + add;
  float pj[BB], cv[BB];
#pragma unroll
  for (int b = 0; b < BB; b++)
    pj[b] = fb ? bf2f(((const uint16_t*)pred)[b * LL + j])
               : ((const float*)pred)[b * LL + j];
#pragma unroll
  for (int k = 0; k < BB; k++) cv[k] = (sacc[k * LL + j] + pj[k] * add) / c;
#pragma unroll
  for (int b = 0; b < BB; b++) {
    float t = pj[b];
#pragma unroll
    for (int k = 0; k < BB; k++) t = fmaf(-ssim[b * 8 + k], cv[k], t);
    float v = t * t;
#pragma unroll
    for (int off = 32; off > 0; off >>= 1) v += __shfl_down(v, off, 64);
    if ((threadIdx.x & 63) == 0) unsafeAtomicAdd(&norm2[b], v);
  }
}

// ---------------------------------------------------------------------------
// Stage 4: finalize scalar output.
// ---------------------------------------------------------------------------
__global__ void stage4(const uint8_t* __restrict__ sim,
                       uint8_t* __restrict__ out, float* __restrict__ ws) {
  if (threadIdx.x != 0) return;
  const int* fl = (const int*)ws;
  int fb = fl[1];
  float* norm2 = ws + WS_NORM2;
  float total = 0.f, cntv = 0.f;
  for (int b = 0; b < BB; b++) {
    float rs = 0.f;
    for (int k = 0; k < 8; k++)
      rs += fb ? bf2f(((const uint16_t*)sim)[b * 8 + k])
               : ((const float*)sim)[b * 8 + k];
    if (rs != 0.f) { cntv += 1.f; total += sqrtf(norm2[b]); }
  }
  float res = (cntv == 0.f) ? 0.f : total / fmaxf(cntv, 1.f);
  if (fb) *reinterpret_cast<__hip_bfloat16*>(out) = __float2bfloat16(res);
  else    *reinterpret_cast<float*>(out) = res;
}

extern "C" void kernel_launch(void* const* d_in, const int* in_sizes, int n_in,
                              void* d_out, int out_size, void* d_ws,
                              size_t ws_size, hipStream_t stream) {
  const uint8_t* pred = (const uint8_t*)d_in[0];
  const uint8_t* sim  = (const uint8_t*)d_in[1];
  const uint8_t* adj  = (const uint8_t*)d_in[2];
  const uint8_t* mask = (const uint8_t*)d_in[3];
  float* ws = (float*)d_ws;

  hipMemsetAsync(d_ws, 0, 32 * sizeof(float), stream);  // flags + norm2 only
  detect_kernel<<<1, 256, 0, stream>>>(mask, adj, (int*)d_ws);
  stage1<<<NCB * NCH, 256, 0, stream>>>(mask, adj, pred, ws);
  reduce_kernel<<<BB * LL / 256, 256, 0, stream>>>(ws);
  stage23<<<LL / 256, 256, 0, stream>>>(mask, pred, sim, ws);
  stage4<<<1, 64, 0, stream>>>(sim, (uint8_t*)d_out, ws);
}